// Round 2
// baseline (1481.081 us; speedup 1.0000x reference)
//
#include <hip/hip_runtime.h>
#include <hip/hip_bf16.h>

#define DIMK 3
#define NPTS 30
#define KK   181
#define PP   24360
#define DEMB 190
#define VLD  192   // padded vec row stride (floats)

// ---------------------------------------------------------------------------
// Kernel 1: per-permutation inner embed -> vec (PP x VLD)
// ---------------------------------------------------------------------------
__global__ __launch_bounds__(256) void k_inner(
    const float* __restrict__ M,      // 3 x 30
    const float* __restrict__ Ws_in,  // 181 x 3
    const float* __restrict__ Wd_in,  // 181 x 27
    float* __restrict__ vec)          // PP x VLD
{
    __shared__ float Gs[NPTS * NPTS];       // 900
    __shared__ float WsS[KK * 3];           // 543
    __shared__ float WdS[KK * 27];          // 4887

    const int tid = threadIdx.x;

    for (int i = tid; i < KK * 3; i += 256)  WsS[i] = Ws_in[i];
    for (int i = tid; i < KK * 27; i += 256) WdS[i] = Wd_in[i];
    for (int e = tid; e < NPTS * NPTS; e += 256) {
        int a = e / NPTS, b = e % NPTS;
        Gs[e] = M[a] * M[b] + M[NPTS + a] * M[NPTS + b] + M[2 * NPTS + a] * M[2 * NPTS + b];
    }
    __syncthreads();

    const int wave = tid >> 6;
    const int lane = tid & 63;
    const int p = blockIdx.x * 4 + wave;

    // factorial-number-system decode of itertools.permutations(range(30),3)
    int i0 = p / 812;            // 812 = 29*28
    int r  = p - i0 * 812;
    int i1 = r / 28;
    int i2 = r - i1 * 28;
    int c0 = i0;
    int c1 = i1 + (i1 >= c0 ? 1 : 0);
    int lo = min(c0, c1), hi = max(c0, c1);
    int c2 = i2;
    if (c2 >= lo) c2++;
    if (c2 >= hi) c2++;

    float* vrow = vec + (long)p * VLD;

    if (lane < 9) {
        int i = lane / 3, j = lane % 3;
        int ci = (i == 0) ? c0 : ((i == 1) ? c1 : c2);
        int cj = (j == 0) ? c0 : ((j == 1) ? c1 : c2);
        vrow[lane] = Gs[ci * NPTS + cj];
    }

    const float* g0 = Gs + c0 * NPTS;
    const float* g1 = Gs + c1 * NPTS;
    const float* g2 = Gs + c2 * NPTS;
    const float INF = __builtin_inff();

    for (int it = 0; it < 3; ++it) {
        int k = it * 64 + lane;
        if (k < KK) {
            float w0 = WsS[k * 3 + 0], w1 = WsS[k * 3 + 1], w2 = WsS[k * 3 + 2];
            float v[32];
#pragma unroll
            for (int j = 0; j < NPTS; ++j) {
                float val = w0 * g0[j] + w1 * g1[j] + w2 * g2[j];
                bool excl = (j == c0) | (j == c1) | (j == c2);
                v[j] = excl ? INF : val;
            }
            v[30] = INF;
            v[31] = INF;

#pragma unroll
            for (int sz = 2; sz <= 32; sz <<= 1) {
#pragma unroll
                for (int st = sz >> 1; st >= 1; st >>= 1) {
#pragma unroll
                    for (int i = 0; i < 32; ++i) {
                        int j = i ^ st;
                        if (j > i) {
                            bool up = ((i & sz) == 0);
                            float a = v[i], b = v[j];
                            float mn = fminf(a, b), mx = fmaxf(a, b);
                            v[i] = up ? mn : mx;
                            v[j] = up ? mx : mn;
                        }
                    }
                }
            }

            float emb = 0.f;
#pragma unroll
            for (int m = 0; m < 27; ++m) emb += WdS[k * 27 + m] * v[m];
            vrow[9 + k] = emb;
        } else if (k < 183) {
            vrow[9 + k] = 0.f;
        }
    }
}

// ---------------------------------------------------------------------------
// Kernel 2: sm2T[k][p] = dot(vec[p][0:190], Ws_out[k][0:190])
// ---------------------------------------------------------------------------
#define BP  64
#define BK  64
#define DC  96
#define LDT 97

__global__ __launch_bounds__(256) void k_gemm(
    const float* __restrict__ vec,    // PP x VLD
    const float* __restrict__ Wout,   // 181 x 190
    float* __restrict__ sm2T)         // 181 x PP
{
    __shared__ float As[BP * LDT];
    __shared__ float Bs[BK * LDT];

    const int tid = threadIdx.x;
    const int pTile = blockIdx.x * BP;
    const int kTile = blockIdx.y * BK;
    const int tx = tid & 15;
    const int ty = tid >> 4;

    float acc[4][4];
#pragma unroll
    for (int i = 0; i < 4; ++i)
#pragma unroll
        for (int j = 0; j < 4; ++j) acc[i][j] = 0.f;

    for (int ch = 0; ch < 2; ++ch) {
        const int dbase = ch * DC;
        __syncthreads();
        for (int e = tid; e < BP * DC; e += 256) {
            int pl = e / DC, d = e - pl * DC;
            int pg = pTile + pl;
            As[pl * LDT + d] = (pg < PP) ? vec[(long)pg * VLD + dbase + d] : 0.f;
        }
        for (int e = tid; e < BK * DC; e += 256) {
            int kl = e / DC, d = e - kl * DC;
            int kg = kTile + kl;
            int dg = dbase + d;
            Bs[kl * LDT + d] = (kg < KK && dg < DEMB) ? Wout[kg * DEMB + dg] : 0.f;
        }
        __syncthreads();

        for (int d = 0; d < DC; ++d) {
            float a[4], b[4];
#pragma unroll
            for (int i = 0; i < 4; ++i) a[i] = As[(tx + 16 * i) * LDT + d];
#pragma unroll
            for (int j = 0; j < 4; ++j) b[j] = Bs[(ty + 16 * j) * LDT + d];
#pragma unroll
            for (int i = 0; i < 4; ++i)
#pragma unroll
                for (int j = 0; j < 4; ++j) acc[i][j] += a[i] * b[j];
        }
    }

#pragma unroll
    for (int j = 0; j < 4; ++j) {
        int kg = kTile + ty + 16 * j;
        if (kg < KK) {
#pragma unroll
            for (int i = 0; i < 4; ++i) {
                int pg = pTile + tx + 16 * i;
                if (pg < PP) sm2T[(long)kg * PP + pg] = acc[i][j];
            }
        }
    }
}

// ---------------------------------------------------------------------------
// Kernel 3: per-k LSD radix sort (4 x 8-bit) of the 24360-column, keys held
// in registers (24/thread), one 96 KiB LDS scatter buffer + 16 KiB per-wave
// histograms. Stable via wave-contiguous chunks + match_any lane ranking.
// Then out[k] = sum_r Wd_out[k][r] * sorted[r].
// ---------------------------------------------------------------------------
#define SN     24576            // padded to 1024*24
#define WAVES  16
#define WCHUNK 1536             // SN / WAVES
#define CPT    24               // keys per thread (= iterations per wave)

__device__ __forceinline__ unsigned long long matchany8(unsigned d) {
    unsigned long long m = ~0ull;
#pragma unroll
    for (int b = 0; b < 8; ++b) {
        unsigned bit = (d >> b) & 1u;
        unsigned long long bal = __ballot(bit);
        m &= bit ? bal : ~bal;
    }
    return m;
}

__global__ __launch_bounds__(1024) void k_sort(
    const float* __restrict__ sm2T,   // 181 x PP
    const float* __restrict__ WdOut,  // 181 x PP
    float* __restrict__ out)          // 181
{
    __shared__ unsigned keys[SN];           // 96 KiB scatter buffer
    __shared__ unsigned cnt[WAVES * 256];   // 16 KiB per-wave histograms
    __shared__ unsigned tot[256];
    __shared__ float red[WAVES];

    const int tid  = threadIdx.x;
    const int wave = tid >> 6;
    const int lane = tid & 63;
    const int k    = blockIdx.x;
    const float* col = sm2T + (long)k * PP;

    const int base_idx = wave * WCHUNK + lane;
    const unsigned long long lt_mask = (1ull << lane) - 1ull;

    // load + encode to monotone u32 keys (registers)
    unsigned key[CPT];
#pragma unroll
    for (int j = 0; j < CPT; ++j) {
        int idx = base_idx + j * 64;
        unsigned u;
        if (idx < PP) {
            unsigned raw = __float_as_uint(col[idx]);
            u = (raw & 0x80000000u) ? ~raw : (raw | 0x80000000u);
        } else {
            u = 0xFFFFFFFFu;   // pad sorts last
        }
        key[j] = u;
    }

    for (int pass = 0; pass < 4; ++pass) {
        const int sh = pass * 8;

        // zero histograms
        for (int i = tid; i < WAVES * 256; i += 1024) cnt[i] = 0;
        __syncthreads();

        // phase 1: per-wave digit counts (leader adds group size)
#pragma unroll
        for (int j = 0; j < CPT; ++j) {
            unsigned d = (key[j] >> sh) & 255u;
            unsigned long long m = matchany8(d);
            int leader = __ffsll((unsigned long long)m) - 1;
            if (lane == leader)
                atomicAdd(&cnt[wave * 256 + d], (unsigned)__popcll(m));
        }
        __syncthreads();

        // phase 2a: per-digit exclusive prefix across waves
        if (tid < 256) {
            unsigned run = 0;
            for (int w = 0; w < WAVES; ++w) {
                unsigned t = cnt[w * 256 + tid];
                cnt[w * 256 + tid] = run;
                run += t;
            }
            tot[tid] = run;
        }
        __syncthreads();

        // phase 2b: inclusive scan over tot[256] (Hillis-Steele)
        for (int off = 1; off < 256; off <<= 1) {
            unsigned v = 0;
            if (tid < 256 && tid >= off) v = tot[tid - off];
            __syncthreads();
            if (tid < 256) tot[tid] += v;
            __syncthreads();
        }

        // phase 2c: cnt[w][d] += exclusive digit base
        for (int i = tid; i < WAVES * 256; i += 1024) {
            int d = i & 255;
            unsigned db = (d == 0) ? 0u : tot[d - 1];
            cnt[i] += db;
        }
        __syncthreads();

        // phase 3: rank & scatter (stable: iteration-major, lane-minor order)
#pragma unroll
        for (int j = 0; j < CPT; ++j) {
            unsigned d = (key[j] >> sh) & 255u;
            unsigned long long m = matchany8(d);
            int leader = __ffsll((unsigned long long)m) - 1;
            unsigned myrank = (unsigned)__popcll(m & lt_mask);
            unsigned old = 0;
            if (lane == leader)
                old = atomicAdd(&cnt[wave * 256 + d], (unsigned)__popcll(m));
            old = __shfl(old, leader, 64);
            keys[old + myrank] = key[j];
        }
        __syncthreads();

        // phase 4: gather back to registers in fixed traversal order
#pragma unroll
        for (int j = 0; j < CPT; ++j) key[j] = keys[base_idx + j * 64];
        __syncthreads();
    }

    // keys[] in LDS now holds the fully sorted column (pads at the end).
    const float* wrow = WdOut + (long)k * PP;
    float local = 0.f;
    for (int r = tid; r < PP; r += 1024) {
        unsigned u = keys[r];
        unsigned raw = (u & 0x80000000u) ? (u & 0x7FFFFFFFu) : ~u;
        local += wrow[r] * __uint_as_float(raw);
    }

#pragma unroll
    for (int off = 32; off > 0; off >>= 1)
        local += __shfl_down(local, off, 64);
    if (lane == 0) red[wave] = local;
    __syncthreads();
    if (tid < WAVES) {
        float x = red[tid];
#pragma unroll
        for (int off = 8; off > 0; off >>= 1)
            x += __shfl_down(x, off, 64);
        if (tid == 0) out[k] = x;
    }
}

// ---------------------------------------------------------------------------
extern "C" void kernel_launch(void* const* d_in, const int* in_sizes, int n_in,
                              void* d_out, int out_size, void* d_ws, size_t ws_size,
                              hipStream_t stream) {
    const float* M      = (const float*)d_in[0];
    const float* Ws_in  = (const float*)d_in[1];
    const float* Wd_in  = (const float*)d_in[2];
    const float* Ws_out = (const float*)d_in[3];
    const float* Wd_out = (const float*)d_in[4];
    float* out = (float*)d_out;

    float* vec  = (float*)d_ws;                    // PP*VLD floats = 18.7 MB
    float* sm2T = vec + (size_t)PP * VLD;          // KK*PP floats  = 17.6 MB

    k_inner<<<PP / 4, 256, 0, stream>>>(M, Ws_in, Wd_in, vec);

    dim3 g2((PP + BP - 1) / BP, (KK + BK - 1) / BK);
    k_gemm<<<g2, 256, 0, stream>>>(vec, Ws_out, sm2T);

    k_sort<<<KK, 1024, 0, stream>>>(sm2T, Wd_out, out);
}